// Round 4
// baseline (137.162 us; speedup 1.0000x reference)
//
#include <hip/hip_runtime.h>
#include <hip/hip_bf16.h>

#define D 128

typedef short bf16x8 __attribute__((ext_vector_type(8)));
typedef float f32x4 __attribute__((ext_vector_type(4)));
typedef float f32x2 __attribute__((ext_vector_type(2)));

__device__ __forceinline__ unsigned short f2bf(float x) {
    __hip_bfloat16 h = __float2bfloat16(x);
    return *reinterpret_cast<unsigned short*>(&h);
}
__device__ __forceinline__ float bflo(unsigned int w) { return __uint_as_float(w << 16); }
__device__ __forceinline__ float bfhi(unsigned int w) { return __uint_as_float(w & 0xffff0000u); }

// tanh-form GELU on a packed pair: gelu(z) = z - z/(1+q), q = exp2(z*(2.3022646 + 0.1029466 z^2))
// Overflow-safe (q=inf -> rcp=0 -> gelu=z). |err vs exact erf-GELU| ~5e-4.
__device__ __forceinline__ f32x2 gelu2(f32x2 z) {
    f32x2 z2 = z * z;
    f32x2 c1 = {0.1029466f, 0.1029466f};
    f32x2 c0 = {2.3022646f, 2.3022646f};
    f32x2 xe = z * __builtin_elementwise_fma(z2, c1, c0);
    f32x2 q;
    q.x = __builtin_amdgcn_exp2f(xe.x);
    q.y = __builtin_amdgcn_exp2f(xe.y);
    f32x2 d = q + 1.0f;
    f32x2 r;
    r.x = __builtin_amdgcn_rcpf(d.x);
    r.y = __builtin_amdgcn_rcpf(d.y);
    return __builtin_elementwise_fma(-z, r, z);
}

// exact-ish GELU for the fallback path (erf via A&S 7.1.26)
__device__ __forceinline__ float gelu_erf(float z) {
    float y = fabsf(z) * 0.70710678118654752f;
    float t = __builtin_amdgcn_rcpf(1.0f + 0.3275911f * y);
    float poly = ((((1.061405429f * t - 1.453152027f) * t + 1.421413741f) * t
                   - 0.284496736f) * t + 0.254829592f) * t;
    float e = __expf(-y * y);
    float erfv = 1.0f - poly * e;
    erfv = copysignf(erfv, z);
    return 0.5f * z * (1.0f + erfv);
}

// ---------------- prep0: W1T bf16 fragment-layout transpose + Wc ----------------
// W1T[h][j][k] = bf16(W1[h*128+k][j]);  Wcbf[c][k] = bf16(sum_j W2[k][j] Wp[j][c]), c in [0,16) zero-padded
__global__ __launch_bounds__(256) void prep0_kernel(const float* __restrict__ W1,
                                                    const float* __restrict__ W2,
                                                    const float* __restrict__ Wp,
                                                    unsigned short* __restrict__ W1T,
                                                    unsigned short* __restrict__ Wcbf) {
    const int b = blockIdx.x, t = threadIdx.x;
    if (b < 16) {
        #pragma unroll
        for (int i = 0; i < 8; ++i) {
            int row = b * 16 + i * 2 + (t >> 7);   // 0..255
            int j = t & 127;
            float v = W1[(size_t)row * D + j];
            int h = row >> 7, k = row & 127;
            W1T[(size_t)h * 16384 + j * 128 + k] = f2bf(v);
        }
    } else {
        #pragma unroll
        for (int i = 0; i < 8; ++i) {
            int idx = i * 256 + t;
            int col = idx >> 7, k = idx & 127;
            float acc = 0.f;
            if (col < 5) {
                #pragma unroll 8
                for (int j = 0; j < D; ++j) acc += W2[k * D + j] * Wp[j * 5 + col];
            }
            Wcbf[col * D + k] = f2bf(acc);
        }
    }
}

// ---------------- node transform: one wave per 16-row tile, no LDS, no barrier ----------------
__global__ __launch_bounds__(256) void node_kernel(const float* __restrict__ uf,
                                                   const float* __restrict__ vf,
                                                   const unsigned short* __restrict__ W1T,
                                                   int NU, int NM, int wU,
                                                   unsigned short* __restrict__ Abf,
                                                   unsigned short* __restrict__ Bbf) {
    const int wv = blockIdx.x * 4 + (threadIdx.x >> 6);
    const int l = threadIdx.x & 63;
    const int m16 = l & 15, g4 = l >> 4;

    const float* feat;
    unsigned short* outp;
    int Nn, tile, h;
    if (wv < wU) { feat = uf; outp = Abf; Nn = NU; tile = wv;      h = 0; }
    else         { feat = vf; outp = Bbf; Nn = NM; tile = wv - wU; h = 1; }
    const int r0 = tile * 16;
    if (r0 >= Nn) return;

    const int arow = r0 + m16;
    const bool rok = arow < Nn;
    const float* rp = feat + (size_t)(rok ? arow : 0) * D;

    union { bf16x8 v; unsigned short u[8]; } afr[4];
    #pragma unroll
    for (int kk = 0; kk < 4; ++kk) {
        int k0 = kk * 32 + g4 * 8;
        float4 f0 = make_float4(0.f, 0.f, 0.f, 0.f), f1 = f0;
        if (rok) {
            f0 = *reinterpret_cast<const float4*>(rp + k0);
            f1 = *reinterpret_cast<const float4*>(rp + k0 + 4);
        }
        afr[kk].u[0] = f2bf(f0.x); afr[kk].u[1] = f2bf(f0.y);
        afr[kk].u[2] = f2bf(f0.z); afr[kk].u[3] = f2bf(f0.w);
        afr[kk].u[4] = f2bf(f1.x); afr[kk].u[5] = f2bf(f1.y);
        afr[kk].u[6] = f2bf(f1.z); afr[kk].u[7] = f2bf(f1.w);
    }

    const unsigned short* wt = W1T + (size_t)h * 16384;
    f32x4 acc[8];
    #pragma unroll
    for (int n = 0; n < 8; ++n) acc[n] = (f32x4){0.f, 0.f, 0.f, 0.f};
    #pragma unroll
    for (int n = 0; n < 8; ++n) {
        #pragma unroll
        for (int kk = 0; kk < 4; ++kk) {
            bf16x8 bfr = *reinterpret_cast<const bf16x8*>(
                wt + ((n * 16 + m16) << 7) + kk * 32 + g4 * 8);
            acc[n] = __builtin_amdgcn_mfma_f32_16x16x32_bf16(afr[kk].v, bfr, acc[n], 0, 0, 0);
        }
    }
    #pragma unroll
    for (int n = 0; n < 8; ++n) {
        #pragma unroll
        for (int r = 0; r < 4; ++r) {
            int row = r0 + g4 * 4 + r;
            if (row < Nn) outp[(size_t)row * D + n * 16 + m16] = f2bf(acc[n][r]);
        }
    }
}

// ---------------- edge kernel: software-pipelined 16-edge groups ----------------
__device__ __forceinline__ void issue8(const unsigned short* __restrict__ A,
                                       const unsigned short* __restrict__ B,
                                       int s, int d, int quad, uint4* av, uint4* bv) {
    const unsigned short* ap = A + ((size_t)s << 7) + quad * 8;
    const unsigned short* bp = B + ((size_t)d << 7) + quad * 8;
    #pragma unroll
    for (int kk = 0; kk < 4; ++kk) {
        av[kk] = *reinterpret_cast<const uint4*>(ap + kk * 32);
        bv[kk] = *reinterpret_cast<const uint4*>(bp + kk * 32);
    }
}

__device__ __forceinline__ void compute_store(const uint4* av, const uint4* bv,
                                              const bf16x8* wfrag, float* __restrict__ out,
                                              int g, int E, int er, int quad) {
    f32x4 acc = (f32x4){0.f, 0.f, 0.f, 0.f};
    #pragma unroll
    for (int kk = 0; kk < 4; ++kk) {
        unsigned int aw[4] = {av[kk].x, av[kk].y, av[kk].z, av[kk].w};
        unsigned int bw[4] = {bv[kk].x, bv[kk].y, bv[kk].z, bv[kk].w};
        union { bf16x8 v; unsigned short u[8]; } frag;
        #pragma unroll
        for (int pp = 0; pp < 4; ++pp) {
            f32x2 za = {bflo(aw[pp]), bfhi(aw[pp])};
            f32x2 zb = {bflo(bw[pp]), bfhi(bw[pp])};
            f32x2 gl = gelu2(za + zb);
            frag.u[2 * pp]     = f2bf(gl.x);
            frag.u[2 * pp + 1] = f2bf(gl.y);
        }
        acc = __builtin_amdgcn_mfma_f32_16x16x32_bf16(frag.v, wfrag[kk], acc, 0, 0, 0);
    }
    int e0 = g << 4;
    #pragma unroll
    for (int r = 0; r < 4; ++r) {
        int e = e0 + quad * 4 + r;
        if (er < 5 && e < E) __builtin_nontemporal_store(acc[r], &out[(size_t)e * 5 + er]);
    }
}

__global__ __launch_bounds__(256, 4) void edge_kernel(const unsigned short* __restrict__ A,
                                                      const unsigned short* __restrict__ B,
                                                      const int* __restrict__ src,
                                                      const int* __restrict__ dst,
                                                      const unsigned short* __restrict__ Wcbf,
                                                      float* __restrict__ out, int E) {
    const int l    = threadIdx.x & 63;
    const int er   = l & 15;
    const int quad = l >> 4;
    const int wid  = blockIdx.x * 4 + (threadIdx.x >> 6);
    const int nw   = gridDim.x * 4;

    bf16x8 wfrag[4];
    #pragma unroll
    for (int kk = 0; kk < 4; ++kk)
        wfrag[kk] = *reinterpret_cast<const bf16x8*>(&Wcbf[er * D + kk * 32 + quad * 8]);

    const int G = (E + 15) >> 4;
    if (wid >= G) return;
    const int Gm = G - 1;

    uint4 aA[4], bA[4], aB[4], bB[4];
    int g = wid;
    {
        int s0 = __builtin_nontemporal_load(&src[g * 16 + er]);
        int d0 = __builtin_nontemporal_load(&dst[g * 16 + er]);
        issue8(A, B, s0, d0, quad, aA, bA);
    }
    int gi = (g + nw <= Gm) ? g + nw : g;
    int sN = __builtin_nontemporal_load(&src[gi * 16 + er]);
    int dN = __builtin_nontemporal_load(&dst[gi * 16 + er]);

    while (true) {
        // bufA holds group g; issue g+nw into bufB, prefetch idx for g+2nw
        issue8(A, B, sN, dN, quad, aB, bB);
        {
            int g2 = g + 2 * nw;
            int gj = (g2 <= Gm) ? g2 : g;
            sN = __builtin_nontemporal_load(&src[gj * 16 + er]);
            dN = __builtin_nontemporal_load(&dst[gj * 16 + er]);
        }
        compute_store(aA, bA, wfrag, out, g, E, er, quad);
        g += nw; if (g > Gm) break;

        // bufB holds group g; issue g+nw into bufA, prefetch idx for g+2nw
        issue8(A, B, sN, dN, quad, aA, bA);
        {
            int g2 = g + 2 * nw;
            int gj = (g2 <= Gm) ? g2 : g;
            sN = __builtin_nontemporal_load(&src[gj * 16 + er]);
            dN = __builtin_nontemporal_load(&dst[gj * 16 + er]);
        }
        compute_store(aB, bB, wfrag, out, g, E, er, quad);
        g += nw; if (g > Gm) break;
    }
}

// ---------------- fallback (ws too small): fully fused per-edge ----------------
__global__ __launch_bounds__(256) void fused_fallback(const float* __restrict__ uf,
                                                      const float* __restrict__ vf,
                                                      const int* __restrict__ src,
                                                      const int* __restrict__ dst,
                                                      const float* __restrict__ W1,
                                                      const float* __restrict__ W2,
                                                      const float* __restrict__ Wp,
                                                      float* __restrict__ out, int E) {
    __shared__ unsigned short sW[256 * 128];
    __shared__ float sWc[5 * 128];
    __shared__ float sH[4][256];
    const int t = threadIdx.x;
    #pragma unroll
    for (int i = 0; i < 32; ++i) {
        int f = (i * 256 + t) * 4;
        float4 v = *reinterpret_cast<const float4*>(&W1[f]);
        sW[f + 0] = f2bf(v.x); sW[f + 1] = f2bf(v.y);
        sW[f + 2] = f2bf(v.z); sW[f + 3] = f2bf(v.w);
    }
    for (int idx = t; idx < 640; idx += 256) {
        int c = idx >> 7, k = idx & 127;
        float a = 0.f;
        for (int m = 0; m < 128; ++m) a += W2[k * 128 + m] * Wp[m * 5 + c];
        sWc[c * 128 + k] = a;
    }
    __syncthreads();
    const int wid = t >> 6, l = t & 63;
    const int nw = gridDim.x * 4;
    for (int e = blockIdx.x * 4 + wid; e < E; e += nw) {
        int s = src[e], d0 = dst[e];
        float2 hu = *reinterpret_cast<const float2*>(&uf[(size_t)s * 128 + 2 * l]);
        float2 hv = *reinterpret_cast<const float2*>(&vf[(size_t)d0 * 128 + 2 * l]);
        sH[wid][2 * l] = hu.x; sH[wid][2 * l + 1] = hu.y;
        sH[wid][128 + 2 * l] = hv.x; sH[wid][128 + 2 * l + 1] = hv.y;
        __builtin_amdgcn_wave_barrier();
        float z0 = 0.f, z1 = 0.f;
        for (int k = 0; k < 256; ++k) {
            float h = sH[wid][k];
            z0 += h * __uint_as_float((unsigned int)sW[k * 128 + l] << 16);
            z1 += h * __uint_as_float((unsigned int)sW[k * 128 + l + 64] << 16);
        }
        float g0 = gelu_erf(z0), g1 = gelu_erf(z1);
        float acc[5];
        #pragma unroll
        for (int c = 0; c < 5; ++c)
            acc[c] = g0 * sWc[c * 128 + l] + g1 * sWc[c * 128 + l + 64];
        #pragma unroll
        for (int c = 0; c < 5; ++c) {
            float v = acc[c];
            v += __shfl_xor(v, 1);  v += __shfl_xor(v, 2);
            v += __shfl_xor(v, 4);  v += __shfl_xor(v, 8);
            v += __shfl_xor(v, 16); v += __shfl_xor(v, 32);
            acc[c] = v;
        }
        float v = acc[0];
        if (l == 1) v = acc[1];
        if (l == 2) v = acc[2];
        if (l == 3) v = acc[3];
        if (l == 4) v = acc[4];
        if (l < 5) out[(size_t)e * 5 + l] = v;
        __builtin_amdgcn_wave_barrier();
    }
}

extern "C" void kernel_launch(void* const* d_in, const int* in_sizes, int n_in,
                              void* d_out, int out_size, void* d_ws, size_t ws_size,
                              hipStream_t stream) {
    const float* ufeat = (const float*)d_in[0];
    const float* ifeat = (const float*)d_in[1];
    const int*   src   = (const int*)d_in[2];
    const int*   dst   = (const int*)d_in[3];
    const float* W1    = (const float*)d_in[4];
    const float* W2    = (const float*)d_in[5];
    const float* Wp    = (const float*)d_in[6];
    float* out = (float*)d_out;

    const int NU = in_sizes[0] / D;
    const int NM = in_sizes[1] / D;
    const int E  = in_sizes[2];

    size_t off_W1T = 4096;                              // Wcbf @ [0,4KB)
    size_t off_A   = off_W1T + 65536;                   // W1T = 64KB
    size_t szA     = (size_t)NU * D * 2;
    size_t off_B   = off_A + ((szA + 255) / 256) * 256;
    size_t need    = off_B + (size_t)NM * D * 2;

    if (ws_size >= need) {
        unsigned short* Wcbf = (unsigned short*)d_ws;
        unsigned short* W1T  = (unsigned short*)((char*)d_ws + off_W1T);
        unsigned short* Abf  = (unsigned short*)((char*)d_ws + off_A);
        unsigned short* Bbf  = (unsigned short*)((char*)d_ws + off_B);

        prep0_kernel<<<dim3(17), dim3(256), 0, stream>>>(W1, W2, Wp, W1T, Wcbf);

        int wU = (NU + 15) / 16, wV = (NM + 15) / 16;
        int nblk = (wU + wV + 3) / 4;
        node_kernel<<<dim3(nblk), dim3(256), 0, stream>>>(ufeat, ifeat, W1T, NU, NM, wU, Abf, Bbf);

        edge_kernel<<<dim3(1024), dim3(256), 0, stream>>>(Abf, Bbf, src, dst, Wcbf, out, E);
    } else {
        fused_fallback<<<dim3(4096), dim3(256), 0, stream>>>(ufeat, ifeat, src, dst,
                                                             W1, W2, Wp, out, E);
    }
}